// Round 17
// baseline (353.471 us; speedup 1.0000x reference)
//
#include <hip/hip_runtime.h>
#include <hip/hip_bf16.h>

// Problem constants
#define BB   2
#define SS   1024
#define DD   1024
#define HH   8
#define NPP  2
#define NKK  32
#define DKK  64
#define TKK  8
#define NKV_ 1024

typedef __hip_bfloat16 bf16;
typedef __attribute__((ext_vector_type(8))) short bf16x8;
typedef __attribute__((ext_vector_type(4))) float f32x4;

using u32g = __attribute__((address_space(1))) unsigned int;
using u32l = __attribute__((address_space(3))) unsigned int;

// async global->LDS, 16B per lane; LDS dest = wave-uniform base + lane*16
#define GLDS16(g, l) __builtin_amdgcn_global_load_lds((const u32g*)(g), (u32l*)(l), 16, 0, 0)

// ---- scalar/vec conversion helpers ----
__device__ inline unsigned short f2b(float f) {       // RNE f32->bf16
    unsigned x = __float_as_uint(f);
    return (unsigned short)((x + 0x7fffu + ((x >> 16) & 1u)) >> 16);
}
__device__ inline float b2f(unsigned short u) {
    return __uint_as_float(((unsigned)u) << 16);
}

// fp32 -> bf16 convert, 4 elems/thread (single region)
__global__ __launch_bounds__(256) void cvt_bf(const float* __restrict__ src,
                                              bf16* __restrict__ dst, long long n)
{
    long long i = ((long long)blockIdx.x * 256 + threadIdx.x) * 4;
    if (i >= n) return;
    float4 v = *(const float4*)&src[i];
    ushort4 u; u.x = f2b(v.x); u.y = f2b(v.y); u.z = f2b(v.z); u.w = f2b(v.w);
    *(ushort4*)&dst[i] = u;
}

// fused fp32 -> bf16 convert over up to 3 regions (one dispatch)
__global__ __launch_bounds__(256) void cvt_bf3(
    const float* __restrict__ s0, bf16* __restrict__ d0, long long n0,
    const float* __restrict__ s1, bf16* __restrict__ d1, long long n1,
    const float* __restrict__ s2, bf16* __restrict__ d2, long long n2)
{
    long long i = ((long long)blockIdx.x * 256 + threadIdx.x) * 4;
    const float* s; bf16* d;
    if (i < n0)                { s = s0 + i;            d = d0 + i; }
    else if (i < n0 + n1)      { s = s1 + (i - n0);     d = d1 + (i - n0); }
    else if (i < n0 + n1 + n2) { s = s2 + (i - n0 - n1); d = d2 + (i - n0 - n1); }
    else return;
    float4 v = *(const float4*)s;
    ushort4 u; u.x = f2b(v.x); u.y = f2b(v.y); u.z = f2b(v.z); u.w = f2b(v.w);
    *(ushort4*)d = u;
}

// split-K reduction: out[i] = scale * sum_s p[i + s*n], float4 per thread
__global__ __launch_bounds__(256) void reduce_split(
    const float* __restrict__ p, float* __restrict__ out,
    long long n, int nsplit, float scale)
{
    long long i = ((long long)blockIdx.x * 256 + threadIdx.x) * 4;
    if (i >= n) return;
    float4 a = *(const float4*)&p[i];
    for (int s = 1; s < nsplit; ++s) {
        float4 b = *(const float4*)&p[i + (long long)s * n];
        a.x += b.x; a.y += b.y; a.z += b.z; a.w += b.w;
    }
    a.x *= scale; a.y *= scale; a.z *= scale; a.w *= scale;
    *(float4*)&out[i] = a;
}

// ============================================================================
// MFMA bf16 GEMM (m97 structure + T2 XOR swizzle + T1 XCD swizzle + grouped
// rasterization): C[m,n] = scale * sum_k A[m][k] * B[n][k]
// 128x128 tile, BK=64, 4 waves (2x2 of 64x64), mfma_f32_16x16x32_bf16.
// Operands swapped in the MFMA (bfr, af) -> lane holds 4 consecutive C
// columns per acc quad -> direct vector-store epilogue.
// LDS(row, chunk) = global(row, chunk ^ (row&7)), 16B chunks (rule #21).
// GROUP: per-XCD bx-rectangles keep the B panel L2-resident (gx%GROUP==0).
// CAUSAL==1: skip tiles above diagonal. CAUSAL==2: Klim = row0+128.
// MODE==1 (merged q+pq projection): blocks with col0 >= 8192 write fp32,
// UNSCALED, into C2[row*1024 + (col-8192)].
// Split-K via z-slab strides. NOTE: gx*gy*gz % 8 == 0 required.
// [R12: deep-prefetch/counted-vmcnt REGRESSED (T4 null on 2-phase; 128KB
//  LDS halved occupancy). R15/16: dispatch fusions neutral-to-harmful.
//  This is the known-good envelope (~650 TF on K=1024 shapes).]
// ============================================================================
template<typename TC, int CAUSAL, int GROUP, int MODE>
__global__ __launch_bounds__(256) void mgemm(
    const bf16* __restrict__ A, const bf16* __restrict__ B, TC* __restrict__ C,
    int K, int lda, int ldb, int ldc,
    long long sAb, long long sAh, long long sBb, long long sBh,
    long long sCb, long long sCh, int zH, float scale,
    float* __restrict__ C2)
{
    // T1: chunked XCD swizzle over the full linear grid (bijective: nwg%8==0)
    int gx = gridDim.x, gy = gridDim.y;
    int nwg = gx * gy * gridDim.z;
    int hw  = (blockIdx.z * gy + blockIdx.y) * gx + blockIdx.x;
    int w   = (hw & 7) * (nwg >> 3) + (hw >> 3);
    int z  = w / (gx * gy);
    int r  = w % (gx * gy);
    int bx = (r / (gy * GROUP)) * GROUP + (r % GROUP);
    int by = (r / GROUP) % gy;

    int zb = z / zH, zh = z % zH;
    A += (long long)zb * sAb + (long long)zh * sAh;
    B += (long long)zb * sBb + (long long)zh * sBh;
    C += (long long)zb * sCb + (long long)zh * sCh;

    int row0 = by * 128, col0 = bx * 128;
    if (CAUSAL == 1 && col0 > row0 + 127) return;
    int Klim = (CAUSAL == 2) ? min(K, row0 + 128) : K;

    __shared__ short sh[16384];          // As = [0:8192), Bs = [8192:16384)
    short* As = sh;
    short* Bs = sh + 8192;

    int tid = threadIdx.x, wave = tid >> 6, lane = tid & 63;
    int wr = wave >> 1, wc = wave & 1;       // wave's 64x64 quadrant
    int lr = lane & 15, lg = lane >> 4;      // frag row / k-group

    f32x4 zero = {0.f, 0.f, 0.f, 0.f};
    f32x4 acc[4][4];
    #pragma unroll
    for (int m = 0; m < 4; ++m)
        #pragma unroll
        for (int n = 0; n < 4; ++n) acc[m][n] = zero;

    // staging: wave stages 32 rows of A and B per K-step; one GLDS16 = 8 rows.
    int srow = wave * 32 + (lane >> 3);
    int scol = ((lane & 7) ^ (lane >> 3)) * 8;
    int fo = (lg ^ (lr & 7)) * 8;            // frag-read swizzle; kk=1 -> fo^32

    for (int k0 = 0; k0 < Klim; k0 += 64) {
        const bf16* Ak = A + (long long)(row0 + srow) * lda + k0 + scol;
        const bf16* Bk = B + (long long)(col0 + srow) * ldb + k0 + scol;
        #pragma unroll
        for (int i = 0; i < 4; ++i) {
            GLDS16(Ak + (long long)i * 8 * lda, &As[(wave * 32 + i * 8) * 64]);
            GLDS16(Bk + (long long)i * 8 * ldb, &Bs[(wave * 32 + i * 8) * 64]);
        }
        asm volatile("s_waitcnt vmcnt(0)" ::: "memory");
        __syncthreads();

        #pragma unroll
        for (int kk = 0; kk < 2; ++kk) {
            bf16x8 af[4], bfr[4];
            #pragma unroll
            for (int m = 0; m < 4; ++m)
                af[m] = *(const bf16x8*)&As[(wr * 64 + m * 16 + lr) * 64 + (fo ^ (kk * 32))];
            #pragma unroll
            for (int n = 0; n < 4; ++n)
                bfr[n] = *(const bf16x8*)&Bs[(wc * 64 + n * 16 + lr) * 64 + (fo ^ (kk * 32))];
            #pragma unroll
            for (int m = 0; m < 4; ++m)
                #pragma unroll
                for (int n = 0; n < 4; ++n)
                    acc[m][n] = __builtin_amdgcn_mfma_f32_16x16x32_bf16(
                        bfr[n], af[m], acc[m][n], 0, 0, 0);   // swapped -> C^T frag
        }
        __syncthreads();
    }

    // Swapped-output layout: lane holds C[row = m*16+lr][col = n*16+lg*4 +0..3]
    if constexpr (MODE == 1) {
        if (col0 >= 8192) {               // pq region: fp32, unscaled, ld=1024
            #pragma unroll
            for (int m = 0; m < 4; ++m) {
                long long row = row0 + wr * 64 + m * 16 + lr;
                #pragma unroll
                for (int n = 0; n < 4; ++n) {
                    int col = col0 - 8192 + wc * 64 + n * 16 + lg * 4;
                    *(float4*)&C2[row * 1024 + col] = make_float4(
                        acc[m][n][0], acc[m][n][1], acc[m][n][2], acc[m][n][3]);
                }
            }
            return;
        }
    }
    #pragma unroll
    for (int m = 0; m < 4; ++m) {
        long long row = row0 + wr * 64 + m * 16 + lr;
        #pragma unroll
        for (int n = 0; n < 4; ++n) {
            int col = col0 + wc * 64 + n * 16 + lg * 4;
            if constexpr (sizeof(TC) == 2) {
                ushort4 o;
                o.x = f2b(scale * acc[m][n][0]);
                o.y = f2b(scale * acc[m][n][1]);
                o.z = f2b(scale * acc[m][n][2]);
                o.w = f2b(scale * acc[m][n][3]);
                *(ushort4*)&C[row * ldc + col] = o;
            } else {
                *(float4*)&C[row * ldc + col] = make_float4(
                    scale * acc[m][n][0], scale * acc[m][n][1],
                    scale * acc[m][n][2], scale * acc[m][n][3]);
            }
        }
    }
}

// ============================================================================
// pq fixup, split-K=4: exact-fp32 recompute of pq rows s < 64 (both batches).
// grid (16 col-tiles, 4 k-splits, 2 batches) = 128 blocks -> partials P.
// ============================================================================
#define TILE 64
#define KT   16
#define LPAD 4
__global__ __launch_bounds__(256) void pq_fix(
    const float* __restrict__ A, const float* __restrict__ Bm, float* __restrict__ P)
{
    long long zo = (long long)blockIdx.z * 1024 * 1024;   // per-batch row offset
    A += zo;
    int col0 = blockIdx.x * TILE;
    int kbase = blockIdx.y * 256;
    __shared__ float As[KT][TILE + LPAD];
    __shared__ float Bs[KT][TILE + LPAD];
    int tid = threadIdx.x, tx = tid % 16, ty = tid / 16;
    float acc[4][4] = {{0.f}};
    int lr = tid / 4, lk = (tid % 4) * 4;

    for (int k0 = kbase; k0 < kbase + 256; k0 += KT) {
        float4 va = *(const float4*)&A[(long long)lr * 1024 + k0 + lk];
        As[lk + 0][lr] = va.x; As[lk + 1][lr] = va.y;
        As[lk + 2][lr] = va.z; As[lk + 3][lr] = va.w;
        float4 vb = *(const float4*)&Bm[(long long)(col0 + lr) * 1024 + k0 + lk];
        Bs[lk + 0][lr] = vb.x; Bs[lk + 1][lr] = vb.y;
        Bs[lk + 2][lr] = vb.z; Bs[lk + 3][lr] = vb.w;
        __syncthreads();
        #pragma unroll
        for (int kk = 0; kk < KT; ++kk) {
            float a[4], b[4];
            #pragma unroll
            for (int i = 0; i < 4; ++i) a[i] = As[kk][ty * 4 + i];
            #pragma unroll
            for (int j = 0; j < 4; ++j) b[j] = Bs[kk][tx * 4 + j];
            #pragma unroll
            for (int i = 0; i < 4; ++i)
                #pragma unroll
                for (int j = 0; j < 4; ++j)
                    acc[i][j] = fmaf(a[i], b[j], acc[i][j]);
        }
        __syncthreads();
    }
    long long base = ((long long)(blockIdx.y * 2 + blockIdx.z) * 64) * 1024;
    #pragma unroll
    for (int i = 0; i < 4; ++i)
        *(float4*)&P[base + (long long)(ty * 4 + i) * 1024 + col0 + tx * 4] =
            make_float4(acc[i][0], acc[i][1], acc[i][2], acc[i][3]);
}

// reduce the 4 k-split partials; overwrite pqb rows s<64 of each batch
__global__ __launch_bounds__(256) void pq_fix_red(
    const float* __restrict__ P, float* __restrict__ pqb)
{
    long long i4 = ((long long)blockIdx.x * 256 + threadIdx.x) * 4;  // [0,131072)
    if (i4 >= 131072) return;
    float4 a = *(const float4*)&P[i4];
    #pragma unroll
    for (int sp = 1; sp < 4; ++sp) {
        float4 b = *(const float4*)&P[(long long)sp * 131072 + i4];
        a.x += b.x; a.y += b.y; a.z += b.z; a.w += b.w;
    }
    long long z = i4 >> 16, rem = i4 & 65535;
    *(float4*)&pqb[z * 1048576 + rem] = a;
}

// ============================================================================
// Product-key routing via bitonic top-k (1 wave per (b,s,h), 4 waves/block).
// jax.lax.top_k semantics preserved EXACTLY (64-bit keys, ties->lowest idx).
// Stage 2 uses the 20-cell staircase {(i,j): (i+1)(j+1) <= 8} (tie-exact).
// ============================================================================
__device__ inline unsigned ord_f32(float f) {
    unsigned u = __float_as_uint(f);
    return (u >> 31) ? ~u : (u | 0x80000000u);
}
__device__ inline float unord_f32(unsigned m) {
    unsigned u = (m >> 31) ? (m ^ 0x80000000u) : ~m;
    return __uint_as_float(u);
}

__global__ __launch_bounds__(256) void pk_route(
    const float* __restrict__ pq, const float* __restrict__ pkk,
    float* __restrict__ wts, int* __restrict__ idxs)
{
    int bid  = blockIdx.x * 4 + (threadIdx.x >> 6);   // (b*S+s)*H + h
    int lane = threadIdx.x & 63;
    int h    = bid % HH;
    long long bs = bid / HH;
    int p = lane >> 5, n = lane & 31;

    const float* pv = pq  + (bs * NPP + p) * (HH * DKK) + h * DKK;
    const float* kv = pkk + ((long long)(p * NKK + n) * HH + h) * DKK;
    float s = 0.f;
    #pragma unroll
    for (int d = 0; d < DKK; d += 4) {
        float4 q4 = *(const float4*)&pv[d];
        float4 k4 = *(const float4*)&kv[d];
        s = fmaf(q4.x, k4.x, fmaf(q4.y, k4.y, fmaf(q4.z, k4.z, fmaf(q4.w, k4.w, s))));
    }

    // ---- stage 1: descending bitonic sort-32 within each half ----
    unsigned long long key =
        ((unsigned long long)ord_f32(s) << 32) | (unsigned)(31 - n);
    #pragma unroll
    for (int k = 2; k <= 32; k <<= 1) {
        #pragma unroll
        for (int j = k >> 1; j > 0; j >>= 1) {
            unsigned long long other = __shfl_xor(key, j);
            bool keep_big = ((n & k) == 0) == ((n & j) == 0);
            key = (keep_big == (other > key)) ? other : key;
        }
    }
    float keepv = unord_f32((unsigned)(key >> 32));
    int   keepn = 31 - (int)(key & 31);

    // ---- stage 2: 20-cell staircase candidates, sort-32 per half ----
    int l5 = lane & 31;
    int ii, jj;
    if (l5 < 8)       { ii = 0;       jj = l5; }
    else if (l5 < 12) { ii = 1;       jj = l5 - 8; }
    else if (l5 < 14) { ii = 2;       jj = l5 - 12; }
    else if (l5 < 16) { ii = 3;       jj = l5 - 14; }
    else              { ii = l5 - 12; jj = 0; }      // 16..19 -> (4..7, 0); >=20 pad
    float c0 = __shfl(keepv, ii);
    float c1 = __shfl(keepv, 32 + jj);
    float cv = c0 + c1;
    int fcell = ii * 8 + jj;

    unsigned long long k2 = (l5 < 20)
        ? (((unsigned long long)ord_f32(cv) << 32) | (unsigned)(63 - fcell))
        : 0ull;                                       // pad sorts to the end
    #pragma unroll
    for (int k = 2; k <= 32; k <<= 1) {
        #pragma unroll
        for (int j = k >> 1; j > 0; j >>= 1) {
            unsigned long long other = __shfl_xor(k2, j);
            bool keep_big = ((l5 & k) == 0) == ((l5 & j) == 0);
            k2 = (keep_big == (other > k2)) ? other : k2;
        }
    }
    int   f   = 63 - (int)(k2 & 63);
    float fsv = unord_f32((unsigned)(k2 >> 32));
    int n0 = __shfl(keepn, f >> 3);
    int n1 = __shfl(keepn, 32 + (f & 7));
    int fsi = n0 + n1 * NKK;

    // ---- softmax over the 8 winners (lanes 0..7); rank-0 is the max
    float m0 = __shfl(fsv, 0);
    float e = (lane < TKK) ? expf(fsv - m0) : 0.f;
    float sum = e;
    #pragma unroll
    for (int off = 1; off < 8; off <<= 1) sum += __shfl_xor(sum, off);
    if (lane < TKK) {
        wts[(long long)bid * TKK + lane]  = e / sum;
        idxs[(long long)bid * TKK + lane] = fsi + h * NKV_;
    }
}

// ============================================================================
// Weighted 8-row embedding-bag gather from bf16 tables.
// One block per (b,s,h); thread owns 4 d-elems -> coalesced, low VGPR,
// high occupancy. Writes kb[b,h,s,d] and v in [b,h,s,d] (transposed after).
// ============================================================================
__global__ __launch_bounds__(256) void gather_kv(
    const bf16* __restrict__ keb, const bf16* __restrict__ veb,
    const float* __restrict__ wts, const int* __restrict__ idxs,
    bf16* __restrict__ kb, bf16* __restrict__ vsd)
{
    int bid = blockIdx.x;                 // (b*S+s)*H + h
    int h = bid % HH;
    int bs = bid / HH;
    int b = bs / SS, s = bs % SS;

    float w[TKK]; long long rb[TKK];
    #pragma unroll
    for (int t = 0; t < TKK; ++t) {
        w[t]  = wts[(long long)bid * TKK + t];
        rb[t] = (long long)idxs[(long long)bid * TKK + t] * DD;
    }
    int c0 = threadIdx.x * 4;
    long long off = (((long long)b * HH + h) * SS + s) * DD + c0;

    ushort4 ld[TKK];
    #pragma unroll
    for (int t = 0; t < TKK; ++t) ld[t] = *(const ushort4*)&keb[rb[t] + c0];
    float4 a = {0.f, 0.f, 0.f, 0.f};
    #pragma unroll
    for (int t = 0; t < TKK; ++t) {
        a.x += w[t] * b2f(ld[t].x); a.y += w[t] * b2f(ld[t].y);
        a.z += w[t] * b2f(ld[t].z); a.w += w[t] * b2f(ld[t].w);
    }
    ushort4 o; o.x = f2b(a.x); o.y = f2b(a.y); o.z = f2b(a.z); o.w = f2b(a.w);
    *(ushort4*)&kb[off] = o;

    #pragma unroll
    for (int t = 0; t < TKK; ++t) ld[t] = *(const ushort4*)&veb[rb[t] + c0];
    a = make_float4(0.f, 0.f, 0.f, 0.f);
    #pragma unroll
    for (int t = 0; t < TKK; ++t) {
        a.x += w[t] * b2f(ld[t].x); a.y += w[t] * b2f(ld[t].y);
        a.z += w[t] * b2f(ld[t].z); a.w += w[t] * b2f(ld[t].w);
    }
    o.x = f2b(a.x); o.y = f2b(a.y); o.z = f2b(a.z); o.w = f2b(a.w);
    *(ushort4*)&vsd[off] = o;
}

// ============================================================================
// In-place 1024x1024 bf16 transpose per z-slab via 64x64 tile pair swap.
// ============================================================================
__global__ __launch_bounds__(256) void tr64ip(bf16* __restrict__ m)
{
    __shared__ unsigned short La[64][65];
    __shared__ unsigned short Lb[64][65];
    unsigned short* M = (unsigned short*)m + (long long)blockIdx.y * SS * DD;

    int p = blockIdx.x, ti = 0;
    while (p >= 16 - ti) { p -= 16 - ti; ++ti; }
    int tj = ti + p;
    int a0r = ti * 64, a0c = tj * 64;
    int b0r = tj * 64, b0c = ti * 64;

    int r = threadIdx.x / 16, c4 = (threadIdx.x % 16) * 4;
    #pragma unroll
    for (int i = 0; i < 4; ++i) {
        int sr = r + i * 16;
        ushort4 va = *(const ushort4*)&M[(long long)(a0r + sr) * DD + a0c + c4];
        La[sr][c4] = va.x; La[sr][c4+1] = va.y; La[sr][c4+2] = va.z; La[sr][c4+3] = va.w;
        if (ti != tj) {
            ushort4 vb = *(const ushort4*)&M[(long long)(b0r + sr) * DD + b0c + c4];
            Lb[sr][c4] = vb.x; Lb[sr][c4+1] = vb.y; Lb[sr][c4+2] = vb.z; Lb[sr][c4+3] = vb.w;
        }
    }
    __syncthreads();
    #pragma unroll
    for (int i = 0; i < 4; ++i) {
        int dr = r + i * 16;
        ushort4 va;
        va.x = La[c4][dr]; va.y = La[c4+1][dr]; va.z = La[c4+2][dr]; va.w = La[c4+3][dr];
        *(ushort4*)&M[(long long)(b0r + dr) * DD + b0c + c4] = va;
        if (ti != tj) {
            ushort4 vb;
            vb.x = Lb[c4][dr]; vb.y = Lb[c4+1][dr]; vb.z = Lb[c4+2][dr]; vb.w = Lb[c4+3][dr];
            *(ushort4*)&M[(long long)(a0r + dr) * DD + a0c + c4] = vb;
        }
    }
}

// ============================================================================
// Causal softmax, wave-per-row (4 rows/block): 16 elems/lane, shuffle
// reductions, no LDS/barriers. Writes only up to the 128-boundary wlim.
// ============================================================================
__global__ __launch_bounds__(256) void softmax_rows(bf16* __restrict__ sc)
{
    int r    = blockIdx.x * 4 + (threadIdx.x >> 6);   // (b*H+h)*S + sq
    int lane = threadIdx.x & 63;
    int sq   = r % SS;
    unsigned short* row = (unsigned short*)(sc + (long long)r * SS);
    int nvalid = sq + 1;
    int wlim = ((sq >> 7) + 1) << 7;
    int base = lane * 16;

    uint4 u0 = *(const uint4*)&row[base];
    uint4 u1 = *(const uint4*)&row[base + 8];
    unsigned uw[8] = {u0.x, u0.y, u0.z, u0.w, u1.x, u1.y, u1.z, u1.w};

    float v[16];
    float m = -INFINITY;
    #pragma unroll
    for (int i = 0; i < 8; ++i) {
        int j0 = base + i * 2;
        v[i*2]   = (j0     < nvalid) ? __uint_as_float(uw[i] << 16)          : -INFINITY;
        v[i*2+1] = (j0 + 1 < nvalid) ? __uint_as_float(uw[i] & 0xffff0000u) : -INFINITY;
        m = fmaxf(m, fmaxf(v[i*2], v[i*2+1]));
    }
    #pragma unroll
    for (int off = 1; off < 64; off <<= 1) m = fmaxf(m, __shfl_xor(m, off));

    float e[16], ls = 0.f;
    #pragma unroll
    for (int i = 0; i < 16; ++i) {
        e[i] = (base + i < nvalid) ? expf(v[i] - m) : 0.f;
        ls += e[i];
    }
    #pragma unroll
    for (int off = 1; off < 64; off <<= 1) ls += __shfl_xor(ls, off);
    float inv = 1.f / ls;

    if (base < wlim) {
        unsigned ow[8];
        #pragma unroll
        for (int i = 0; i < 8; ++i)
            ow[i] = (unsigned)f2b(e[i*2] * inv) | ((unsigned)f2b(e[i*2+1] * inv) << 16);
        *(uint4*)&row[base]     = make_uint4(ow[0], ow[1], ow[2], ow[3]);
        *(uint4*)&row[base + 8] = make_uint4(ow[4], ow[5], ow[6], ow[7]);
    }
}

extern "C" void kernel_launch(void* const* d_in, const int* in_sizes, int n_in,
                              void* d_out, int out_size, void* d_ws, size_t ws_size,
                              hipStream_t stream)
{
    const float* inputs     = (const float*)d_in[0];
    const float* Wq         = (const float*)d_in[1];
    const float* Wpk        = (const float*)d_in[2];
    const float* pk_keys    = (const float*)d_in[3];
    const float* keys_emb   = (const float*)d_in[4];
    const float* values_emb = (const float*)d_in[5];
    const float* Wo         = (const float*)d_in[6];
    float* out = (float*)d_out;

    // ---- workspace layout (129 MB, aliased) ----
    const long long MB = 1LL << 20;
    char* base = (char*)d_ws;
    bf16* kb   = (bf16*)(base);           // [B,H,S,D] 32MB (gather -> QK)
    bf16* Wob  = (bf16*)(base);           // [0:16MB) bf16 Wo (after QK; kb dead)
    float* spl2 = (float*)(base + 16*MB); // pq_fix split-K partials [16:18MB)
    bf16* qc  = (bf16*)(base + 32*MB);    // q then ctx, [B,S,H*D]  32MB
    bf16* vt  = (bf16*)(base + 64*MB);    // v: [B,H,S,D] then in-place [B,H,D,S]
    float* spl8 = (float*)(base + 64*MB); // step-9 split-K=8 partials, 64MB
                                          // (vt+scb region, dead after PV)
    char* screg = base + 96*MB;           // 32MB multi-use region
    bf16* scb = (bf16*)screg;             // scores [B*H,S,S]
    float* pqb = (float*)screg;           // [0:8MB)   pq fp32
    bf16* Wqb  = (bf16*)(screg + 8*MB);   // [8:24MB)  bf16 Wq  (merged B rows 0..8191)
    bf16* Wpkb = (bf16*)(screg + 24*MB);  // [24:26MB) bf16 Wpk (rows 8192..9215)
    bf16* xb   = (bf16*)(screg + 26*MB);  // [26:30MB) bf16 inputs
    bf16* keb  = (bf16*)screg;            // [0:16MB)  bf16 keys_emb
    bf16* veb  = (bf16*)(screg + 16*MB);  // [16:32MB) bf16 values_emb
    float* wtb = (float*)(base + 128*MB); // routing weights fp32
    int*   ixb = (int*)(base + 128*MB + (512<<10));
    size_t needed = (size_t)(129*MB);
    if (ws_size < needed) return;

    const long long SLAB = (long long)SS * HH * DD;     // 8,388,608
    const long long SD   = (long long)SS * DD;          // 1,048,576
    const long long OUTN = 2048LL * 1024;               // 2,097,152

    // 0. fused bf16 copies: inputs -> xb, Wq -> Wqb, Wpk -> Wpkb
    cvt_bf3<<<dim3(11264), 256, 0, stream>>>(
        inputs, xb, 2097152LL, Wq, Wqb, 8388608LL, Wpk, Wpkb, 1048576LL);

    // 1. pq fixup partials (fp32 exact, rows s<64), split-K=4 -> spl2
    pq_fix<<<dim3(16, 4, 2), 256, 0, stream>>>(inputs, Wpk, spl2);

    // 2. MERGED projection: q (bf16, *d^-0.5) + pq (fp32) in one GEMM.
    mgemm<bf16, 0, 8, 1><<<dim3(72, 16, 1), 256, 0, stream>>>(
        xb, Wqb, qc, 1024, 1024, 1024, 8192,
        0, 0, 0, 0, 0, 0, 1, 0.03125f, pqb);

    // 2b. overwrite pq rows s<64 with the exact-fp32 reduction
    pq_fix_red<<<dim3(128), 256, 0, stream>>>(spl2, pqb);

    // 3. product-key routing (bitonic + staircase)
    pk_route<<<dim3(BB * SS * HH / 4), 256, 0, stream>>>(pqb, pk_keys, wtb, ixb);

    // 4. fused bf16 embedding tables (projection inputs now dead)
    cvt_bf3<<<dim3(16384), 256, 0, stream>>>(
        keys_emb, keb, 8388608LL, values_emb, veb, 8388608LL,
        (const float*)nullptr, (bf16*)nullptr, 0LL);

    // 5. gather: kb[b,h,s,d] + v[b,h,s,d]
    gather_kv<<<dim3(BB * SS * HH), 256, 0, stream>>>(
        keb, veb, wtb, ixb, kb, vt);

    // 5b. in-place transpose v -> [b,h,d,s]
    tr64ip<<<dim3(136, BB * HH), 256, 0, stream>>>(vt);

    // 6. scores = q @ k^T per (b,h), causal tile-skip -> scb (tables dead)
    mgemm<bf16, 1, 1, 0><<<dim3(8, 8, BB * HH), 256, 0, stream>>>(
        qc, kb, scb, 1024, 8192, 1024, 1024,
        SLAB, (long long)DD, (long long)HH * SD, SD,
        (long long)HH * SS * SS, (long long)SS * SS, HH, 1.0f, nullptr);

    // 7. causal softmax
    softmax_rows<<<dim3(BB * HH * SS / 4), 256, 0, stream>>>(scb);

    // 8. ctx = att @ v (B = vt), K limited to row0+128; ctx -> qc slab
    mgemm<bf16, 2, 1, 0><<<dim3(8, 8, BB * HH), 256, 0, stream>>>(
        scb, vt, qc, 1024, 1024, 1024, 8192,
        (long long)HH * SS * SS, (long long)SS * SS,
        (long long)HH * SD, SD,
        SLAB, (long long)DD, HH, 1.0f, nullptr);

    // 8b. bf16 Wo -> base[0:16MB) (kb dead after QK)
    cvt_bf<<<dim3(8192), 256, 0, stream>>>(Wo, Wob, 8388608LL);

    // 9. out = ctx @ Wo^T, split-K=8 (K=1024 each, 1024 blocks) -> partials
    //    in spl8 (vt+scb dead), then 8-way reduce
    mgemm<float, 0, 1, 0><<<dim3(8, 16, 8), 256, 0, stream>>>(
        qc, Wob, spl8, 1024, 8192, 8192, 1024,
        1024, 0, 1024, 0, OUTN, 0, 1, 1.0f, nullptr);
    reduce_split<<<dim3(2048), 256, 0, stream>>>(spl8, out, OUTN, 8, 1.0f);
}

// Round 18
// 344.929 us; speedup vs baseline: 1.0248x; 1.0248x over previous
//
#include <hip/hip_runtime.h>
#include <hip/hip_bf16.h>

// Problem constants
#define BB   2
#define SS   1024
#define DD   1024
#define HH   8
#define NPP  2
#define NKK  32
#define DKK  64
#define TKK  8
#define NKV_ 1024

typedef __hip_bfloat16 bf16;
typedef __attribute__((ext_vector_type(8))) short bf16x8;
typedef __attribute__((ext_vector_type(4))) float f32x4;

using u32g = __attribute__((address_space(1))) unsigned int;
using u32l = __attribute__((address_space(3))) unsigned int;

// async global->LDS, 16B per lane; LDS dest = wave-uniform base + lane*16
#define GLDS16(g, l) __builtin_amdgcn_global_load_lds((const u32g*)(g), (u32l*)(l), 16, 0, 0)

// ---- scalar/vec conversion helpers ----
__device__ inline unsigned short f2b(float f) {       // RNE f32->bf16
    unsigned x = __float_as_uint(f);
    return (unsigned short)((x + 0x7fffu + ((x >> 16) & 1u)) >> 16);
}
__device__ inline float b2f(unsigned short u) {
    return __uint_as_float(((unsigned)u) << 16);
}

// fp32 -> bf16 convert, 4 elems/thread (single region)
__global__ __launch_bounds__(256) void cvt_bf(const float* __restrict__ src,
                                              bf16* __restrict__ dst, long long n)
{
    long long i = ((long long)blockIdx.x * 256 + threadIdx.x) * 4;
    if (i >= n) return;
    float4 v = *(const float4*)&src[i];
    ushort4 u; u.x = f2b(v.x); u.y = f2b(v.y); u.z = f2b(v.z); u.w = f2b(v.w);
    *(ushort4*)&dst[i] = u;
}

// fused fp32 -> bf16 convert over up to 3 regions (one dispatch)
__global__ __launch_bounds__(256) void cvt_bf3(
    const float* __restrict__ s0, bf16* __restrict__ d0, long long n0,
    const float* __restrict__ s1, bf16* __restrict__ d1, long long n1,
    const float* __restrict__ s2, bf16* __restrict__ d2, long long n2)
{
    long long i = ((long long)blockIdx.x * 256 + threadIdx.x) * 4;
    const float* s; bf16* d;
    if (i < n0)                { s = s0 + i;            d = d0 + i; }
    else if (i < n0 + n1)      { s = s1 + (i - n0);     d = d1 + (i - n0); }
    else if (i < n0 + n1 + n2) { s = s2 + (i - n0 - n1); d = d2 + (i - n0 - n1); }
    else return;
    float4 v = *(const float4*)s;
    ushort4 u; u.x = f2b(v.x); u.y = f2b(v.y); u.z = f2b(v.z); u.w = f2b(v.w);
    *(ushort4*)d = u;
}

// split-K reduction: out[i] = scale * sum_s p[i + s*n], float4 per thread
__global__ __launch_bounds__(256) void reduce_split(
    const float* __restrict__ p, float* __restrict__ out,
    long long n, int nsplit, float scale)
{
    long long i = ((long long)blockIdx.x * 256 + threadIdx.x) * 4;
    if (i >= n) return;
    float4 a = *(const float4*)&p[i];
    for (int s = 1; s < nsplit; ++s) {
        float4 b = *(const float4*)&p[i + (long long)s * n];
        a.x += b.x; a.y += b.y; a.z += b.z; a.w += b.w;
    }
    a.x *= scale; a.y *= scale; a.z *= scale; a.w *= scale;
    *(float4*)&out[i] = a;
}

// ============================================================================
// MFMA bf16 GEMM (m97 structure + T2 XOR swizzle + T1 XCD swizzle + grouped
// rasterization): C[m,n] = scale * sum_k A[m][k] * B[n][k]
// 128x128 tile, BK=64, 4 waves (2x2 of 64x64), mfma_f32_16x16x32_bf16.
// OPERANDS SWAPPED in the MFMA call (bfr, af) -> lane holds 4 consecutive C
// columns per acc quad -> direct vector-store epilogue.
// LDS(row, chunk) = global(row, chunk ^ (row&7)), 16B chunks (rule #21).
// GROUP: per-XCD bx-rectangles keep the B panel L2-resident (gx%GROUP==0).
// CAUSAL==1: skip tiles above diagonal. CAUSAL==2: Klim = row0+128.
// MODE==1 (merged q+pq projection): blocks with col0 >= 8192 write fp32,
// UNSCALED, into C2[row*1024 + (col-8192)].
// Split-K via z-slab strides. NOTE: gx*gy*gz % 8 == 0 required.
// [Session ledger: R12 deep-prefetch/counted-vmcnt REGRESSED (T4 null on
//  2-phase; 128KB LDS halved occupancy). R15/R16 dispatch fusions
//  neutral-to-harmful. R17 split-K=8 on Wo regressed (partial-traffic
//  doubling > occupancy gain). This config (R14) = session best, 345 µs.]
// ============================================================================
template<typename TC, int CAUSAL, int GROUP, int MODE>
__global__ __launch_bounds__(256) void mgemm(
    const bf16* __restrict__ A, const bf16* __restrict__ B, TC* __restrict__ C,
    int K, int lda, int ldb, int ldc,
    long long sAb, long long sAh, long long sBb, long long sBh,
    long long sCb, long long sCh, int zH, float scale,
    float* __restrict__ C2)
{
    // T1: chunked XCD swizzle over the full linear grid (bijective: nwg%8==0)
    int gx = gridDim.x, gy = gridDim.y;
    int nwg = gx * gy * gridDim.z;
    int hw  = (blockIdx.z * gy + blockIdx.y) * gx + blockIdx.x;
    int w   = (hw & 7) * (nwg >> 3) + (hw >> 3);
    // grouped decomposition: bx-groups of width GROUP, by fastest within group
    int z  = w / (gx * gy);
    int r  = w % (gx * gy);
    int bx = (r / (gy * GROUP)) * GROUP + (r % GROUP);
    int by = (r / GROUP) % gy;

    int zb = z / zH, zh = z % zH;
    A += (long long)zb * sAb + (long long)zh * sAh;
    B += (long long)zb * sBb + (long long)zh * sBh;
    C += (long long)zb * sCb + (long long)zh * sCh;

    int row0 = by * 128, col0 = bx * 128;
    if (CAUSAL == 1 && col0 > row0 + 127) return;
    int Klim = (CAUSAL == 2) ? min(K, row0 + 128) : K;

    __shared__ short sh[16384];          // As = [0:8192), Bs = [8192:16384)
    short* As = sh;
    short* Bs = sh + 8192;

    int tid = threadIdx.x, wave = tid >> 6, lane = tid & 63;
    int wr = wave >> 1, wc = wave & 1;       // wave's 64x64 quadrant
    int lr = lane & 15, lg = lane >> 4;      // frag row / k-group

    f32x4 zero = {0.f, 0.f, 0.f, 0.f};
    f32x4 acc[4][4];
    #pragma unroll
    for (int m = 0; m < 4; ++m)
        #pragma unroll
        for (int n = 0; n < 4; ++n) acc[m][n] = zero;

    // staging: wave stages 32 rows of A and B per K-step; one GLDS16 = 8 rows.
    int srow = wave * 32 + (lane >> 3);
    int scol = ((lane & 7) ^ (lane >> 3)) * 8;
    int fo = (lg ^ (lr & 7)) * 8;            // frag-read swizzle; kk=1 -> fo^32

    for (int k0 = 0; k0 < Klim; k0 += 64) {
        const bf16* Ak = A + (long long)(row0 + srow) * lda + k0 + scol;
        const bf16* Bk = B + (long long)(col0 + srow) * ldb + k0 + scol;
        #pragma unroll
        for (int i = 0; i < 4; ++i) {
            GLDS16(Ak + (long long)i * 8 * lda, &As[(wave * 32 + i * 8) * 64]);
            GLDS16(Bk + (long long)i * 8 * ldb, &Bs[(wave * 32 + i * 8) * 64]);
        }
        asm volatile("s_waitcnt vmcnt(0)" ::: "memory");
        __syncthreads();

        #pragma unroll
        for (int kk = 0; kk < 2; ++kk) {
            bf16x8 af[4], bfr[4];
            #pragma unroll
            for (int m = 0; m < 4; ++m)
                af[m] = *(const bf16x8*)&As[(wr * 64 + m * 16 + lr) * 64 + (fo ^ (kk * 32))];
            #pragma unroll
            for (int n = 0; n < 4; ++n)
                bfr[n] = *(const bf16x8*)&Bs[(wc * 64 + n * 16 + lr) * 64 + (fo ^ (kk * 32))];
            #pragma unroll
            for (int m = 0; m < 4; ++m)
                #pragma unroll
                for (int n = 0; n < 4; ++n)
                    acc[m][n] = __builtin_amdgcn_mfma_f32_16x16x32_bf16(
                        bfr[n], af[m], acc[m][n], 0, 0, 0);   // swapped -> C^T frag
        }
        __syncthreads();
    }

    // Swapped-output layout: lane holds C[row = m*16+lr][col = n*16+lg*4 +0..3]
    if constexpr (MODE == 1) {
        if (col0 >= 8192) {               // pq region: fp32, unscaled, ld=1024
            #pragma unroll
            for (int m = 0; m < 4; ++m) {
                long long row = row0 + wr * 64 + m * 16 + lr;
                #pragma unroll
                for (int n = 0; n < 4; ++n) {
                    int col = col0 - 8192 + wc * 64 + n * 16 + lg * 4;
                    *(float4*)&C2[row * 1024 + col] = make_float4(
                        acc[m][n][0], acc[m][n][1], acc[m][n][2], acc[m][n][3]);
                }
            }
            return;
        }
    }
    #pragma unroll
    for (int m = 0; m < 4; ++m) {
        long long row = row0 + wr * 64 + m * 16 + lr;
        #pragma unroll
        for (int n = 0; n < 4; ++n) {
            int col = col0 + wc * 64 + n * 16 + lg * 4;
            if constexpr (sizeof(TC) == 2) {
                ushort4 o;
                o.x = f2b(scale * acc[m][n][0]);
                o.y = f2b(scale * acc[m][n][1]);
                o.z = f2b(scale * acc[m][n][2]);
                o.w = f2b(scale * acc[m][n][3]);
                *(ushort4*)&C[row * ldc + col] = o;
            } else {
                *(float4*)&C[row * ldc + col] = make_float4(
                    scale * acc[m][n][0], scale * acc[m][n][1],
                    scale * acc[m][n][2], scale * acc[m][n][3]);
            }
        }
    }
}

// ============================================================================
// pq fixup, split-K=4: exact-fp32 recompute of pq rows s < 64 (both batches).
// grid (16 col-tiles, 4 k-splits, 2 batches) = 128 blocks -> partials P.
// ============================================================================
#define TILE 64
#define KT   16
#define LPAD 4
__global__ __launch_bounds__(256) void pq_fix(
    const float* __restrict__ A, const float* __restrict__ Bm, float* __restrict__ P)
{
    long long zo = (long long)blockIdx.z * 1024 * 1024;   // per-batch row offset
    A += zo;
    int col0 = blockIdx.x * TILE;
    int kbase = blockIdx.y * 256;
    __shared__ float As[KT][TILE + LPAD];
    __shared__ float Bs[KT][TILE + LPAD];
    int tid = threadIdx.x, tx = tid % 16, ty = tid / 16;
    float acc[4][4] = {{0.f}};
    int lr = tid / 4, lk = (tid % 4) * 4;

    for (int k0 = kbase; k0 < kbase + 256; k0 += KT) {
        float4 va = *(const float4*)&A[(long long)lr * 1024 + k0 + lk];
        As[lk + 0][lr] = va.x; As[lk + 1][lr] = va.y;
        As[lk + 2][lr] = va.z; As[lk + 3][lr] = va.w;
        float4 vb = *(const float4*)&Bm[(long long)(col0 + lr) * 1024 + k0 + lk];
        Bs[lk + 0][lr] = vb.x; Bs[lk + 1][lr] = vb.y;
        Bs[lk + 2][lr] = vb.z; Bs[lk + 3][lr] = vb.w;
        __syncthreads();
        #pragma unroll
        for (int kk = 0; kk < KT; ++kk) {
            float a[4], b[4];
            #pragma unroll
            for (int i = 0; i < 4; ++i) a[i] = As[kk][ty * 4 + i];
            #pragma unroll
            for (int j = 0; j < 4; ++j) b[j] = Bs[kk][tx * 4 + j];
            #pragma unroll
            for (int i = 0; i < 4; ++i)
                #pragma unroll
                for (int j = 0; j < 4; ++j)
                    acc[i][j] = fmaf(a[i], b[j], acc[i][j]);
        }
        __syncthreads();
    }
    long long base = ((long long)(blockIdx.y * 2 + blockIdx.z) * 64) * 1024;
    #pragma unroll
    for (int i = 0; i < 4; ++i)
        *(float4*)&P[base + (long long)(ty * 4 + i) * 1024 + col0 + tx * 4] =
            make_float4(acc[i][0], acc[i][1], acc[i][2], acc[i][3]);
}

// reduce the 4 k-split partials; overwrite pqb rows s<64 of each batch
__global__ __launch_bounds__(256) void pq_fix_red(
    const float* __restrict__ P, float* __restrict__ pqb)
{
    long long i4 = ((long long)blockIdx.x * 256 + threadIdx.x) * 4;  // [0,131072)
    if (i4 >= 131072) return;
    float4 a = *(const float4*)&P[i4];
    #pragma unroll
    for (int sp = 1; sp < 4; ++sp) {
        float4 b = *(const float4*)&P[(long long)sp * 131072 + i4];
        a.x += b.x; a.y += b.y; a.z += b.z; a.w += b.w;
    }
    long long z = i4 >> 16, rem = i4 & 65535;
    *(float4*)&pqb[z * 1048576 + rem] = a;
}

// ============================================================================
// Product-key routing via bitonic top-k (1 wave per (b,s,h), 4 waves/block).
// jax.lax.top_k semantics preserved EXACTLY (64-bit keys, ties->lowest idx).
// Stage 2 uses the 20-cell staircase {(i,j): (i+1)(j+1) <= 8}: any cell
// outside it has >=8 weakly-dominating cells with smaller flat index, so it
// can never be in the top-8 under value-desc/index-asc order (tie-exact).
// ============================================================================
__device__ inline unsigned ord_f32(float f) {
    unsigned u = __float_as_uint(f);
    return (u >> 31) ? ~u : (u | 0x80000000u);
}
__device__ inline float unord_f32(unsigned m) {
    unsigned u = (m >> 31) ? (m ^ 0x80000000u) : ~m;
    return __uint_as_float(u);
}

__global__ __launch_bounds__(256) void pk_route(
    const float* __restrict__ pq, const float* __restrict__ pkk,
    float* __restrict__ wts, int* __restrict__ idxs)
{
    int bid  = blockIdx.x * 4 + (threadIdx.x >> 6);   // (b*S+s)*H + h
    int lane = threadIdx.x & 63;
    int h    = bid % HH;
    long long bs = bid / HH;
    int p = lane >> 5, n = lane & 31;

    const float* pv = pq  + (bs * NPP + p) * (HH * DKK) + h * DKK;
    const float* kv = pkk + ((long long)(p * NKK + n) * HH + h) * DKK;
    float s = 0.f;
    #pragma unroll
    for (int d = 0; d < DKK; d += 4) {
        float4 q4 = *(const float4*)&pv[d];
        float4 k4 = *(const float4*)&kv[d];
        s = fmaf(q4.x, k4.x, fmaf(q4.y, k4.y, fmaf(q4.z, k4.z, fmaf(q4.w, k4.w, s))));
    }

    // ---- stage 1: descending bitonic sort-32 within each half ----
    unsigned long long key =
        ((unsigned long long)ord_f32(s) << 32) | (unsigned)(31 - n);
    #pragma unroll
    for (int k = 2; k <= 32; k <<= 1) {
        #pragma unroll
        for (int j = k >> 1; j > 0; j >>= 1) {
            unsigned long long other = __shfl_xor(key, j);
            bool keep_big = ((n & k) == 0) == ((n & j) == 0);
            key = (keep_big == (other > key)) ? other : key;
        }
    }
    float keepv = unord_f32((unsigned)(key >> 32));
    int   keepn = 31 - (int)(key & 31);

    // ---- stage 2: 20-cell staircase candidates, sort-32 per half ----
    int l5 = lane & 31;
    int ii, jj;
    if (l5 < 8)       { ii = 0;       jj = l5; }
    else if (l5 < 12) { ii = 1;       jj = l5 - 8; }
    else if (l5 < 14) { ii = 2;       jj = l5 - 12; }
    else if (l5 < 16) { ii = 3;       jj = l5 - 14; }
    else              { ii = l5 - 12; jj = 0; }      // 16..19 -> (4..7, 0); >=20 pad
    float c0 = __shfl(keepv, ii);
    float c1 = __shfl(keepv, 32 + jj);
    float cv = c0 + c1;
    int fcell = ii * 8 + jj;

    unsigned long long k2 = (l5 < 20)
        ? (((unsigned long long)ord_f32(cv) << 32) | (unsigned)(63 - fcell))
        : 0ull;                                       // pad sorts to the end
    #pragma unroll
    for (int k = 2; k <= 32; k <<= 1) {
        #pragma unroll
        for (int j = k >> 1; j > 0; j >>= 1) {
            unsigned long long other = __shfl_xor(k2, j);
            bool keep_big = ((l5 & k) == 0) == ((l5 & j) == 0);
            k2 = (keep_big == (other > k2)) ? other : k2;
        }
    }
    int   f   = 63 - (int)(k2 & 63);
    float fsv = unord_f32((unsigned)(k2 >> 32));
    int n0 = __shfl(keepn, f >> 3);
    int n1 = __shfl(keepn, 32 + (f & 7));
    int fsi = n0 + n1 * NKK;

    // ---- softmax over the 8 winners (lanes 0..7); rank-0 is the max
    float m0 = __shfl(fsv, 0);
    float e = (lane < TKK) ? expf(fsv - m0) : 0.f;
    float sum = e;
    #pragma unroll
    for (int off = 1; off < 8; off <<= 1) sum += __shfl_xor(sum, off);
    if (lane < TKK) {
        wts[(long long)bid * TKK + lane]  = e / sum;
        idxs[(long long)bid * TKK + lane] = fsi + h * NKV_;
    }
}

// ============================================================================
// Weighted 8-row embedding-bag gather from bf16 tables.
// One block per (b,s,h); thread owns 4 d-elems -> coalesced, low VGPR,
// high occupancy. Writes kb[b,h,s,d] and v in [b,h,s,d] (transposed after).
// ============================================================================
__global__ __launch_bounds__(256) void gather_kv(
    const bf16* __restrict__ keb, const bf16* __restrict__ veb,
    const float* __restrict__ wts, const int* __restrict__ idxs,
    bf16* __restrict__ kb, bf16* __restrict__ vsd)
{
    int bid = blockIdx.x;                 // (b*S+s)*H + h
    int h = bid % HH;
    int bs = bid / HH;
    int b = bs / SS, s = bs % SS;

    float w[TKK]; long long rb[TKK];
    #pragma unroll
    for (int t = 0; t < TKK; ++t) {
        w[t]  = wts[(long long)bid * TKK + t];
        rb[t] = (long long)idxs[(long long)bid * TKK + t] * DD;
    }
    int c0 = threadIdx.x * 4;
    long long off = (((long long)b * HH + h) * SS + s) * DD + c0;

    ushort4 ld[TKK];
    #pragma unroll
    for (int t = 0; t < TKK; ++t) ld[t] = *(const ushort4*)&keb[rb[t] + c0];
    float4 a = {0.f, 0.f, 0.f, 0.f};
    #pragma unroll
    for (int t = 0; t < TKK; ++t) {
        a.x += w[t] * b2f(ld[t].x); a.y += w[t] * b2f(ld[t].y);
        a.z += w[t] * b2f(ld[t].z); a.w += w[t] * b2f(ld[t].w);
    }
    ushort4 o; o.x = f2b(a.x); o.y = f2b(a.y); o.z = f2b(a.z); o.w = f2b(a.w);
    *(ushort4*)&kb[off] = o;

    #pragma unroll
    for (int t = 0; t < TKK; ++t) ld[t] = *(const ushort4*)&veb[rb[t] + c0];
    a = make_float4(0.f, 0.f, 0.f, 0.f);
    #pragma unroll
    for (int t = 0; t < TKK; ++t) {
        a.x += w[t] * b2f(ld[t].x); a.y += w[t] * b2f(ld[t].y);
        a.z += w[t] * b2f(ld[t].z); a.w += w[t] * b2f(ld[t].w);
    }
    o.x = f2b(a.x); o.y = f2b(a.y); o.z = f2b(a.z); o.w = f2b(a.w);
    *(ushort4*)&vsd[off] = o;
}

// ============================================================================
// In-place 1024x1024 bf16 transpose per z-slab via 64x64 tile pair swap.
// ============================================================================
__global__ __launch_bounds__(256) void tr64ip(bf16* __restrict__ m)
{
    __shared__ unsigned short La[64][65];
    __shared__ unsigned short Lb[64][65];
    unsigned short* M = (unsigned short*)m + (long long)blockIdx.y * SS * DD;

    int p = blockIdx.x, ti = 0;
    while (p >= 16 - ti) { p -= 16 - ti; ++ti; }
    int tj = ti + p;
    int a0r = ti * 64, a0c = tj * 64;
    int b0r = tj * 64, b0c = ti * 64;

    int r = threadIdx.x / 16, c4 = (threadIdx.x % 16) * 4;
    #pragma unroll
    for (int i = 0; i < 4; ++i) {
        int sr = r + i * 16;
        ushort4 va = *(const ushort4*)&M[(long long)(a0r + sr) * DD + a0c + c4];
        La[sr][c4] = va.x; La[sr][c4+1] = va.y; La[sr][c4+2] = va.z; La[sr][c4+3] = va.w;
        if (ti != tj) {
            ushort4 vb = *(const ushort4*)&M[(long long)(b0r + sr) * DD + b0c + c4];
            Lb[sr][c4] = vb.x; Lb[sr][c4+1] = vb.y; Lb[sr][c4+2] = vb.z; Lb[sr][c4+3] = vb.w;
        }
    }
    __syncthreads();
    #pragma unroll
    for (int i = 0; i < 4; ++i) {
        int dr = r + i * 16;
        ushort4 va;
        va.x = La[c4][dr]; va.y = La[c4+1][dr]; va.z = La[c4+2][dr]; va.w = La[c4+3][dr];
        *(ushort4*)&M[(long long)(b0r + dr) * DD + b0c + c4] = va;
        if (ti != tj) {
            ushort4 vb;
            vb.x = Lb[c4][dr]; vb.y = Lb[c4+1][dr]; vb.z = Lb[c4+2][dr]; vb.w = Lb[c4+3][dr];
            *(ushort4*)&M[(long long)(a0r + dr) * DD + a0c + c4] = vb;
        }
    }
}

// ============================================================================
// Causal softmax, wave-per-row (4 rows/block): 16 elems/lane, shuffle
// reductions, no LDS/barriers. Writes only up to the 128-boundary wlim.
// ============================================================================
__global__ __launch_bounds__(256) void softmax_rows(bf16* __restrict__ sc)
{
    int r    = blockIdx.x * 4 + (threadIdx.x >> 6);   // (b*H+h)*S + sq
    int lane = threadIdx.x & 63;
    int sq   = r % SS;
    unsigned short* row = (unsigned short*)(sc + (long long)r * SS);
    int nvalid = sq + 1;
    int wlim = ((sq >> 7) + 1) << 7;
    int base = lane * 16;

    uint4 u0 = *(const uint4*)&row[base];
    uint4 u1 = *(const uint4*)&row[base + 8];
    unsigned uw[8] = {u0.x, u0.y, u0.z, u0.w, u1.x, u1.y, u1.z, u1.w};

    float v[16];
    float m = -INFINITY;
    #pragma unroll
    for (int i = 0; i < 8; ++i) {
        int j0 = base + i * 2;
        v[i*2]   = (j0     < nvalid) ? __uint_as_float(uw[i] << 16)          : -INFINITY;
        v[i*2+1] = (j0 + 1 < nvalid) ? __uint_as_float(uw[i] & 0xffff0000u) : -INFINITY;
        m = fmaxf(m, fmaxf(v[i*2], v[i*2+1]));
    }
    #pragma unroll
    for (int off = 1; off < 64; off <<= 1) m = fmaxf(m, __shfl_xor(m, off));

    float e[16], ls = 0.f;
    #pragma unroll
    for (int i = 0; i < 16; ++i) {
        e[i] = (base + i < nvalid) ? expf(v[i] - m) : 0.f;
        ls += e[i];
    }
    #pragma unroll
    for (int off = 1; off < 64; off <<= 1) ls += __shfl_xor(ls, off);
    float inv = 1.f / ls;

    if (base < wlim) {
        unsigned ow[8];
        #pragma unroll
        for (int i = 0; i < 8; ++i)
            ow[i] = (unsigned)f2b(e[i*2] * inv) | ((unsigned)f2b(e[i*2+1] * inv) << 16);
        *(uint4*)&row[base]     = make_uint4(ow[0], ow[1], ow[2], ow[3]);
        *(uint4*)&row[base + 8] = make_uint4(ow[4], ow[5], ow[6], ow[7]);
    }
}

extern "C" void kernel_launch(void* const* d_in, const int* in_sizes, int n_in,
                              void* d_out, int out_size, void* d_ws, size_t ws_size,
                              hipStream_t stream)
{
    const float* inputs     = (const float*)d_in[0];
    const float* Wq         = (const float*)d_in[1];
    const float* Wpk        = (const float*)d_in[2];
    const float* pk_keys    = (const float*)d_in[3];
    const float* keys_emb   = (const float*)d_in[4];
    const float* values_emb = (const float*)d_in[5];
    const float* Wo         = (const float*)d_in[6];
    float* out = (float*)d_out;

    // ---- workspace layout (129 MB, aliased) ----
    const long long MB = 1LL << 20;
    char* base = (char*)d_ws;
    bf16* kb  = (bf16*)(base);            // [B,H,S,D]  32MB  (also step-9 partials)
    float* spl = (float*)base;            // step-9 split-K partials [0:32MB)
    float* spl2 = (float*)(base + 16*MB); // pq_fix split-K partials [16:18MB)
    bf16* qc  = (bf16*)(base + 32*MB);    // q then ctx, [B,S,H*D]  32MB
    bf16* vt  = (bf16*)(base + 64*MB);    // v: [B,H,S,D] then in-place [B,H,D,S]
    char* screg = base + 96*MB;           // 32MB multi-use region
    bf16* scb = (bf16*)screg;             // scores [B*H,S,S]
    float* pqb = (float*)screg;           // [0:8MB)   pq fp32
    bf16* Wqb  = (bf16*)(screg + 8*MB);   // [8:24MB)  bf16 Wq  (merged B rows 0..8191)
    bf16* Wpkb = (bf16*)(screg + 24*MB);  // [24:26MB) bf16 Wpk (rows 8192..9215)
    bf16* xb   = (bf16*)(screg + 26*MB);  // [26:30MB) bf16 inputs
    bf16* keb  = (bf16*)screg;            // [0:16MB)  bf16 keys_emb
    bf16* veb  = (bf16*)(screg + 16*MB);  // [16:32MB) bf16 values_emb
    bf16* Wob  = (bf16*)screg;            // [0:16MB)  bf16 Wo (after scores dead)
    float* wtb = (float*)(base + 128*MB); // routing weights fp32
    int*   ixb = (int*)(base + 128*MB + (512<<10));
    size_t needed = (size_t)(129*MB);
    if (ws_size < needed) return;

    const long long SLAB = (long long)SS * HH * DD;     // 8,388,608
    const long long SD   = (long long)SS * DD;          // 1,048,576
    const long long OUTN = 2048LL * 1024;               // 2,097,152

    // 0. fused bf16 copies: inputs -> xb, Wq -> Wqb, Wpk -> Wpkb
    //    (Wqb and Wpkb are contiguous -> one [9216][1024] B matrix)
    cvt_bf3<<<dim3(11264), 256, 0, stream>>>(
        inputs, xb, 2097152LL, Wq, Wqb, 8388608LL, Wpk, Wpkb, 1048576LL);

    // 1. pq fixup partials (fp32 exact, rows s<64), split-K=4 -> spl2
    pq_fix<<<dim3(16, 4, 2), 256, 0, stream>>>(inputs, Wpk, spl2);

    // 2. MERGED projection: q (bf16, *d^-0.5) + pq (fp32) in one GEMM.
    //    N=9216: cols 0..8191 -> qc, cols 8192..9215 -> pqb. GROUP=8.
    mgemm<bf16, 0, 8, 1><<<dim3(72, 16, 1), 256, 0, stream>>>(
        xb, Wqb, qc, 1024, 1024, 1024, 8192,
        0, 0, 0, 0, 0, 0, 1, 0.03125f, pqb);

    // 2b. overwrite pq rows s<64 with the exact-fp32 reduction
    pq_fix_red<<<dim3(128), 256, 0, stream>>>(spl2, pqb);

    // 3. product-key routing -> fp32 weights + row indices (bitonic+staircase)
    pk_route<<<dim3(BB * SS * HH / 4), 256, 0, stream>>>(pqb, pk_keys, wtb, ixb);

    // 4. fused bf16 embedding tables (projection inputs now dead)
    cvt_bf3<<<dim3(16384), 256, 0, stream>>>(
        keys_emb, keb, 8388608LL, values_emb, veb, 8388608LL,
        (const float*)nullptr, (bf16*)nullptr, 0LL);

    // 5. gather: kb[b,h,s,d] + v[b,h,s,d] (high-occupancy structure)
    gather_kv<<<dim3(BB * SS * HH), 256, 0, stream>>>(
        keb, veb, wtb, ixb, kb, vt);

    // 5b. in-place transpose v -> [b,h,d,s]
    tr64ip<<<dim3(136, BB * HH), 256, 0, stream>>>(vt);

    // 6. scores = q @ k^T per (b,h), causal tile-skip -> scb (tables dead)
    mgemm<bf16, 1, 1, 0><<<dim3(8, 8, BB * HH), 256, 0, stream>>>(
        qc, kb, scb, 1024, 8192, 1024, 1024,
        SLAB, (long long)DD, (long long)HH * SD, SD,
        (long long)HH * SS * SS, (long long)SS * SS, HH, 1.0f, nullptr);

    // 7. causal softmax (wave-per-row, shuffle reductions)
    softmax_rows<<<dim3(BB * HH * SS / 4), 256, 0, stream>>>(scb);

    // 8. ctx = att @ v (B = vt), K limited to row0+128; ctx -> qc slab
    mgemm<bf16, 2, 1, 0><<<dim3(8, 8, BB * HH), 256, 0, stream>>>(
        scb, vt, qc, 1024, 1024, 1024, 8192,
        (long long)HH * SS * SS, (long long)SS * SS,
        (long long)HH * SD, SD,
        SLAB, (long long)DD, HH, 1.0f, nullptr);

    // 8b. bf16 Wo (scores dead now)
    cvt_bf<<<dim3(8192), 256, 0, stream>>>(Wo, Wob, 8388608LL);

    // 9. out = ctx @ Wo^T, split-K=4 -> partials in spl (kb dead), reduce
    mgemm<float, 0, 1, 0><<<dim3(8, 16, 4), 256, 0, stream>>>(
        qc, Wob, spl, 2048, 8192, 8192, 1024,
        2048, 0, 2048, 0, OUTN, 0, 1, 1.0f, nullptr);
    reduce_split<<<dim3(2048), 256, 0, stream>>>(spl, out, OUTN, 4, 1.0f);
}